// Round 5
// baseline (437.677 us; speedup 1.0000x reference)
//
#include <hip/hip_runtime.h>
#include <math.h>

// N=8192 tokens, D=1024. All inputs fp32.
// out = (E@g)/l + gate*colsum(g) + x
// E = exp(c*q_hat@k_hat^T - beta_j), beta_j = c*mean(q_hat)·k_hat_j  (row-uniform
// centering terms cancel in E/rowsum(E)); gate = exp(m)/sum(exp(m)), no max needed.
// R5: low-register MX fp8 core (in-place v8i halves, per-j B loads) for BOTH
// k_score and k_out. R3's MX regression was VGPR bloat (92 regs, occ 20%), not
// amortization: fp8-core b64 reads carry a structural 4-way bank conflict
// (measured 4.0 cyc/instr) making LDS the binding pipe; MX b128 is conflict-free.

#define NT 8192
#define DD 1024

typedef float v4f __attribute__((ext_vector_type(4)));
typedef short v8s __attribute__((ext_vector_type(8)));
typedef int   v4i __attribute__((ext_vector_type(4)));
typedef int   v8i __attribute__((ext_vector_type(8)));

typedef const __attribute__((address_space(1))) void* gp_t;
typedef __attribute__((address_space(3))) void* lp_t;

__device__ __forceinline__ short f2b(float f) {
    unsigned u = __float_as_uint(f);
    return (short)((u + 0x7fffu + ((u >> 16) & 1u)) >> 16);   // RNE
}
__device__ __forceinline__ char f2e4m3(float f) {
    unsigned p = __builtin_amdgcn_cvt_pk_fp8_f32(f, f, 0, false);
    return (char)(p & 0xff);
}

// supertile swizzle: bands of 16 row-tiles so concurrent blocks share A/B panels in L2/LLC
__device__ __forceinline__ void tile_coords(int bid, int tn, int& bm, int& bn) {
    const int SUP = 16;
    int per = SUP * tn;
    int band = bid / per, r = bid % per;
    bm = band * SUP + (r % SUP);
    bn = r / SUP;
}

// ---------------- bf16 GEMM core (k_proj) ----------------
__device__ __forceinline__ void gemm_core(const short* __restrict__ A,
                                          const short* __restrict__ B,
                                          int K, int m0, int n0,
                                          short* smem, v4f (&acc)[4][4])
{
    short* lsA = smem;            // 128*64 shorts
    short* lsB = smem + 8192;
    const int tid  = threadIdx.x;
    const int wave = tid >> 6, lane = tid & 63;
    const int l15 = lane & 15, l4 = lane >> 4;
    const int wm = (wave >> 1) << 6, wn = (wave & 1) << 6;

#pragma unroll
    for (int i = 0; i < 4; i++)
#pragma unroll
        for (int j = 0; j < 4; j++) acc[i][j] = (v4f)(0.0f);

    const int srow = lane >> 3;
    const int g    = (lane & 7) ^ srow;

    for (int k0 = 0; k0 < K; k0 += 64) {
#pragma unroll
        for (int i = 0; i < 4; i++) {
            int ci  = wave * 4 + i;
            int row = ci * 8 + srow;
            const short* ga = A + (size_t)(m0 + row) * K + k0 + g * 8;
            const short* gb = B + (size_t)(n0 + row) * K + k0 + g * 8;
            __builtin_amdgcn_global_load_lds((gp_t)ga, (lp_t)(lsA + ci * 512), 16, 0, 0);
            __builtin_amdgcn_global_load_lds((gp_t)gb, (lp_t)(lsB + ci * 512), 16, 0, 0);
        }
        __syncthreads();
#pragma unroll
        for (int kk = 0; kk < 64; kk += 32) {
            v8s af[4], bf[4];
#pragma unroll
            for (int t = 0; t < 4; t++) {
                int ra = wm + t * 16 + l15;
                int ca = ((kk >> 3) + l4) ^ (ra & 7);
                af[t] = *(const v8s*)(lsA + ra * 64 + ca * 8);
                int rb = wn + t * 16 + l15;
                int cb = ((kk >> 3) + l4) ^ (rb & 7);
                bf[t] = *(const v8s*)(lsB + rb * 64 + cb * 8);
            }
#pragma unroll
            for (int i = 0; i < 4; i++)
#pragma unroll
                for (int j = 0; j < 4; j++)
                    acc[i][j] = __builtin_amdgcn_mfma_f32_16x16x32_bf16(af[i], bf[j], acc[i][j], 0, 0, 0);
        }
        __syncthreads();
    }
}

// ---------------- MX fp8 GEMM core (low-register, R5) ----------------
// A: [M x K] e4m3 row-major (K in BYTES), B: [N x K] e4m3 row-major.
// BK=128 bytes; one 16x16x128 scaled MFMA (unit scales) per (i,j) per staging
// iter. Fragments assembled via 2x in-place b128 loads (c1 = c0^1 since 2*l4
// is even); A-frags resident (32 VGPR), B-frag loaded per-j (8 VGPR transient).
__device__ __forceinline__ void gemm_core_mx(const char* __restrict__ A,
                                             const char* __restrict__ B,
                                             int K, int m0, int n0,
                                             char* smem, v4f (&acc)[4][4])
{
    char* lsA = smem;             // 128 rows * 128 B
    char* lsB = smem + 16384;
    const int tid  = threadIdx.x;
    const int wave = tid >> 6, lane = tid & 63;
    const int l15 = lane & 15, l4 = lane >> 4;
    const int wm = (wave >> 1) << 6, wn = (wave & 1) << 6;

#pragma unroll
    for (int i = 0; i < 4; i++)
#pragma unroll
        for (int j = 0; j < 4; j++) acc[i][j] = (v4f)(0.0f);

    const int srow = lane >> 3;
    const int g    = (lane & 7) ^ srow;

    for (int k0 = 0; k0 < K; k0 += 128) {
#pragma unroll
        for (int i = 0; i < 4; i++) {
            int ci  = wave * 4 + i;
            int row = ci * 8 + srow;
            const char* ga = A + (size_t)(m0 + row) * K + k0 + g * 16;
            const char* gb = B + (size_t)(n0 + row) * K + k0 + g * 16;
            __builtin_amdgcn_global_load_lds((gp_t)ga, (lp_t)(lsA + ci * 1024), 16, 0, 0);
            __builtin_amdgcn_global_load_lds((gp_t)gb, (lp_t)(lsB + ci * 1024), 16, 0, 0);
        }
        __syncthreads();
        v8i af[4];
#pragma unroll
        for (int t = 0; t < 4; t++) {
            int ra = wm + t * 16 + l15;
            int c0 = (2 * l4) ^ (ra & 7);
            *(v4i*)&af[t]       = *(const v4i*)(lsA + ra * 128 + c0 * 16);
            *((v4i*)&af[t] + 1) = *(const v4i*)(lsA + ra * 128 + (c0 ^ 1) * 16);
        }
#pragma unroll
        for (int j = 0; j < 4; j++) {
            v8i bq;
            int rb = wn + j * 16 + l15;
            int c0 = (2 * l4) ^ (rb & 7);
            *(v4i*)&bq       = *(const v4i*)(lsB + rb * 128 + c0 * 16);
            *((v4i*)&bq + 1) = *(const v4i*)(lsB + rb * 128 + (c0 ^ 1) * 16);
#pragma unroll
            for (int i = 0; i < 4; i++)
                acc[i][j] = __builtin_amdgcn_mfma_scale_f32_16x16x128_f8f6f4(
                    af[i], bq, acc[i][j], 0, 0,
                    0, 0x7f7f7f7f, 0, 0x7f7f7f7f);   // e8m0 0x7f = 1.0
        }
        __syncthreads();
    }
}

// ---------------- small kernels ----------------

// Fused: x -> bf16 xb; m = x.Wm + b; em = exp(m); gden += em (block-reduced atomic).
__global__ void x_prep(const float* __restrict__ x, const float* __restrict__ wv,
                       const float* __restrict__ bp, short* __restrict__ xb,
                       float* __restrict__ em, float* __restrict__ gden) {
    __shared__ float sred[4];
    int wv_id = threadIdx.x >> 6;
    int row = blockIdx.x * 4 + wv_id;
    int lane = threadIdx.x & 63;
    const float* xr = x + (size_t)row * DD;
    short* xbr = xb + (size_t)row * DD;
    float s = 0.f;
    for (int c = lane * 4; c < DD; c += 256) {
        float4 a = *(const float4*)(xr + c);
        float4 b = *(const float4*)(wv + c);
        s = fmaf(a.x, b.x, s); s = fmaf(a.y, b.y, s);
        s = fmaf(a.z, b.z, s); s = fmaf(a.w, b.w, s);
        short4 o;
        o.x = f2b(a.x); o.y = f2b(a.y); o.z = f2b(a.z); o.w = f2b(a.w);
        *(short4*)(xbr + c) = o;
    }
    for (int o = 32; o; o >>= 1) s += __shfl_down(s, o);
    if (lane == 0) {
        float e = __expf(s + bp[0]);
        em[row] = e;
        sred[wv_id] = e;
    }
    __syncthreads();
    if (threadIdx.x == 0)
        atomicAdd(gden, sred[0] + sred[1] + sred[2] + sred[3]);
}

__global__ void cvt_w(const float* __restrict__ Wq, const float* __restrict__ Wk,
                      const float* __restrict__ Wg, short* __restrict__ wbt) {
    __shared__ float t[64][68];
    const float* W = blockIdx.z == 0 ? Wq : (blockIdx.z == 1 ? Wk : Wg);
    int k0 = blockIdx.x * 64, n0 = blockIdx.y * 64;
    int tr = threadIdx.x >> 4, tc = threadIdx.x & 15;
#pragma unroll
    for (int p = 0; p < 4; p++) {
        int r = p * 16 + tr;
        float4 v = *(const float4*)(W + (size_t)(k0 + r) * DD + n0 + tc * 4);
        t[r][tc * 4 + 0] = v.x; t[r][tc * 4 + 1] = v.y;
        t[r][tc * 4 + 2] = v.z; t[r][tc * 4 + 3] = v.w;
    }
    __syncthreads();
#pragma unroll
    for (int p = 0; p < 4; p++) {
        int rr = p * 16 + tr;
        short4 s;
        s.x = f2b(t[tc * 4 + 0][rr]); s.y = f2b(t[tc * 4 + 1][rr]);
        s.z = f2b(t[tc * 4 + 2][rr]); s.w = f2b(t[tc * 4 + 3][rr]);
        *(short4*)(wbt + (size_t)(blockIdx.z * DD + n0 + rr) * DD + k0 + tc * 4) = s;
    }
}

// beta[j] = (c/NT) * sum_d qsum[d] * k8[j][d]   (one wave per row)
__global__ void beta_gemv(const char* __restrict__ k8, const float* __restrict__ qsum,
                          const float* __restrict__ cp, float* __restrict__ beta) {
    int row = blockIdx.x * 4 + (threadIdx.x >> 6);
    int lane = threadIdx.x & 63;
    v4i kv = *(const v4i*)(k8 + (size_t)row * DD + lane * 16);
    const float* qs = qsum + lane * 16;
    float s = 0.f;
#pragma unroll
    for (int w = 0; w < 4; w++) {
        float4 qv = *(const float4*)(qs + w * 4);
        int word = kv[w];
        s = fmaf(__builtin_amdgcn_cvt_f32_fp8(word, 0), qv.x, s);
        s = fmaf(__builtin_amdgcn_cvt_f32_fp8(word, 1), qv.y, s);
        s = fmaf(__builtin_amdgcn_cvt_f32_fp8(word, 2), qv.z, s);
        s = fmaf(__builtin_amdgcn_cvt_f32_fp8(word, 3), qv.w, s);
    }
    for (int o = 32; o; o >>= 1) s += __shfl_down(s, o);
    if (lane == 0) beta[row] = s * cp[0] / (float)NT;
}

// ---------------- GEMM kernels ----------------

// K1: C = x @ [Wq|Wk|Wg]  (M=8192, N=3072, K=1024), bf16 MFMA, fp8 outputs
__global__ __launch_bounds__(256, 2) void k_proj(
        const short* __restrict__ xb, const short* __restrict__ wbt,
        char* __restrict__ q8, char* __restrict__ k8, char* __restrict__ gbt,
        float* __restrict__ qsum, float* __restrict__ gsum) {
    __shared__ __align__(16) short smem[16384];
    int bm, bn; tile_coords(blockIdx.x, 24, bm, bn);
    int m0 = bm * 128, n0 = bn * 128;
    v4f acc[4][4];
    gemm_core(xb, wbt, DD, m0, n0, smem, acc);

    const int tid = threadIdx.x, wave = tid >> 6, lane = tid & 63;
    const int l15 = lane & 15, l4 = lane >> 4;
    const int wm = (wave >> 1) << 6, wn = (wave & 1) << 6;
    int sec = n0 >> 10;            // 0=q 1=k 2=g
    int nloc = n0 & (DD - 1);

    if (sec < 2) {
        char* dst = sec ? k8 : q8;
        float cs[4] = {0.f, 0.f, 0.f, 0.f};
#pragma unroll
        for (int i = 0; i < 4; i++)
#pragma unroll
            for (int j = 0; j < 4; j++)
#pragma unroll
                for (int v = 0; v < 4; v++) {
                    int row = m0 + wm + i * 16 + l4 * 4 + v;
                    int col = nloc + wn + j * 16 + l15;
                    dst[(size_t)row * DD + col] = f2e4m3(acc[i][j][v]);
                    cs[j] += acc[i][j][v];
                }
        if (sec == 0)
#pragma unroll
            for (int j = 0; j < 4; j++)
                atomicAdd(&qsum[nloc + wn + j * 16 + l15], cs[j]);
    } else {
        // g tile -> transposed fp8 store gbt[d][i] via LDS bounce
        char* sc = (char*)smem;
        float cs[4] = {0.f, 0.f, 0.f, 0.f};
#pragma unroll
        for (int i = 0; i < 4; i++)
#pragma unroll
            for (int j = 0; j < 4; j++)
#pragma unroll
                for (int v = 0; v < 4; v++) {
                    int lr = wn + j * 16 + l15;            // local d
                    int lc = wm + i * 16 + l4 * 4 + v;     // local token
                    sc[lr * 144 + lc] = f2e4m3(acc[i][j][v]);
                    cs[j] += acc[i][j][v];
                }
        __syncthreads();
#pragma unroll
        for (int it = 0; it < 4; it++) {
            int c = it * 256 + tid;
            int dr = c >> 3, cm = (c & 7) * 16;
            int4 vv = *(const int4*)(sc + dr * 144 + cm);
            *(int4*)(gbt + (size_t)(nloc + dr) * NT + m0 + cm) = vv;
        }
#pragma unroll
        for (int j = 0; j < 4; j++)
            atomicAdd(&gsum[nloc + wn + j * 16 + l15], cs[j]);
    }
}

// K3: E = exp(c*q@k^T - beta_j) e4m3, l += rowsum(E)
__global__ __launch_bounds__(256, 2) void k_score(
        const char* __restrict__ q8, const char* __restrict__ k8,
        char* __restrict__ E, float* __restrict__ l, const float* __restrict__ cptr,
        const float* __restrict__ beta) {
    __shared__ __align__(16) char smem[32768];
    int bm, bn; tile_coords(blockIdx.x, 64, bm, bn);
    int m0 = bm * 128, n0 = bn * 128;
    v4f acc[4][4];
    gemm_core_mx(q8, k8, DD, m0, n0, smem, acc);

    const float cv = cptr[0];
    const int tid = threadIdx.x, wave = tid >> 6, lane = tid & 63;
    const int l15 = lane & 15, l4 = lane >> 4;
    const int wm = (wave >> 1) << 6, wn = (wave & 1) << 6;
    float bj[4];
#pragma unroll
    for (int j = 0; j < 4; j++) bj[j] = beta[n0 + wn + j * 16 + l15];
#pragma unroll
    for (int i = 0; i < 4; i++)
#pragma unroll
        for (int v = 0; v < 4; v++) {
            int row = m0 + wm + i * 16 + l4 * 4 + v;
            float rsum = 0.f;
#pragma unroll
            for (int j = 0; j < 4; j++) {
                float e = __expf(cv * acc[i][j][v] - bj[j]);
                E[(size_t)row * NT + (n0 + wn + j * 16 + l15)] = f2e4m3(e);
                rsum += e;
            }
#pragma unroll
            for (int o = 1; o < 16; o <<= 1) rsum += __shfl_xor(rsum, o);
            if (l15 == 0) atomicAdd(&l[row], rsum);
        }
}

// K4: out = (E @ g)/l + (em/gden)*gsum + x
__global__ __launch_bounds__(256, 2) void k_out(
        const char* __restrict__ E, const char* __restrict__ gbt,
        const float* __restrict__ l, const float* __restrict__ em,
        const float* __restrict__ gden, const float* __restrict__ gsum,
        const float* __restrict__ x, float* __restrict__ out) {
    __shared__ __align__(16) char smem[32768];
    int bm, bn; tile_coords(blockIdx.x, 8, bm, bn);
    int m0 = bm * 128, n0 = bn * 128;
    v4f acc[4][4];
    gemm_core_mx(E, gbt, NT, m0, n0, smem, acc);

    const float ginv = 1.f / gden[0];
    const int tid = threadIdx.x, wave = tid >> 6, lane = tid & 63;
    const int l15 = lane & 15, l4 = lane >> 4;
    const int wm = (wave >> 1) << 6, wn = (wave & 1) << 6;
#pragma unroll
    for (int i = 0; i < 4; i++)
#pragma unroll
        for (int v = 0; v < 4; v++) {
            int row = m0 + wm + i * 16 + l4 * 4 + v;
            float inv = 1.f / l[row];
            float gv  = em[row] * ginv;
#pragma unroll
            for (int j = 0; j < 4; j++) {
                int col = n0 + wn + j * 16 + l15;
                out[(size_t)row * DD + col] =
                    acc[i][j][v] * inv + gv * gsum[col] + x[(size_t)row * DD + col];
            }
        }
}

// ---------------- launch ----------------

extern "C" void kernel_launch(void* const* d_in, const int* in_sizes, int n_in,
                              void* d_out, int out_size, void* d_ws, size_t ws_size,
                              hipStream_t stream) {
    const float* x  = (const float*)d_in[0];
    const float* Wq = (const float*)d_in[1];
    const float* Wk = (const float*)d_in[2];
    const float* Wg = (const float*)d_in[3];
    const float* Wm = (const float*)d_in[4];
    const float* Wb = (const float*)d_in[5];
    const float* cp = (const float*)d_in[6];
    float* out = (float*)d_out;

    char* w = (char*)d_ws;
    size_t off = 0;
    auto alloc = [&](size_t bytes) -> void* {
        void* p = w + off;
        off += (bytes + 255) & ~(size_t)255;
        return p;
    };
    char*  q8    = (char*)alloc((size_t)NT * DD);           // 8 MB fp8 q_hat
    char*  k8    = (char*)alloc((size_t)NT * DD);           // 8 MB fp8 k_hat
    char*  gbt   = (char*)alloc((size_t)DD * NT);           // 8 MB fp8 g^T
    short* wbt   = (short*)alloc((size_t)3 * DD * DD * 2);  // 6 MB
    short* xb    = (short*)alloc((size_t)NT * DD * 2);      // 16 MB
    char*  E     = (char*)alloc((size_t)NT * NT);           // 64 MB fp8
    float* stats = (float*)alloc((2 * DD + 3 * NT + 1) * 4);
    float* qsum = stats;
    float* gsum = stats + DD;
    float* lrow = stats + 2 * DD;
    float* gden = lrow + NT;               // zeroed region: [stats, gden] inclusive
    float* em   = gden + 1;
    float* beta = em + NT;
    if (off > ws_size) return;

    hipMemsetAsync(stats, 0, (size_t)(2 * DD + NT + 1) * 4, stream);

    x_prep<<<NT / 4, 256, 0, stream>>>(x, Wm, Wb, xb, em, gden);
    cvt_w<<<dim3(16, 16, 3), 256, 0, stream>>>(Wq, Wk, Wg, wbt);
    k_proj<<<64 * 24, 256, 0, stream>>>(xb, wbt, q8, k8, gbt, qsum, gsum);
    beta_gemv<<<NT / 4, 256, 0, stream>>>(k8, qsum, cp, beta);
    k_score<<<64 * 64, 256, 0, stream>>>(q8, k8, E, lrow, cp, beta);
    k_out<<<64 * 8, 256, 0, stream>>>(E, gbt, lrow, em, gden, gsum, x, out);
}

// Round 6
// 407.263 us; speedup vs baseline: 1.0747x; 1.0747x over previous
//
#include <hip/hip_runtime.h>
#include <math.h>

// N=8192 tokens, D=1024. All inputs fp32.
// out = (E@g)/l + gate*colsum(g) + x
// E = exp(c*q_hat@k_hat^T - beta_j), beta_j = c*mean(q_hat)·k_hat_j  (row-uniform
// centering terms cancel in E/rowsum(E)); gate = exp(m)/sum(exp(m)), no max needed.
// R6: dispatch-count reduction (8 -> 5): prep = memset+x_prep+cvt_w fused;
// beta_gemv absorbs gden reduction. GEMM cores frozen at R4-best:
// k_proj bf16, k_score non-scaled fp8 (120us), k_out MX v1 (~55us).

#define NT 8192
#define DD 1024

typedef float v4f __attribute__((ext_vector_type(4)));
typedef short v8s __attribute__((ext_vector_type(8)));
typedef int   v4i __attribute__((ext_vector_type(4)));
typedef int   v8i __attribute__((ext_vector_type(8)));

typedef const __attribute__((address_space(1))) void* gp_t;
typedef __attribute__((address_space(3))) void* lp_t;

__device__ __forceinline__ short f2b(float f) {
    unsigned u = __float_as_uint(f);
    return (short)((u + 0x7fffu + ((u >> 16) & 1u)) >> 16);   // RNE
}
__device__ __forceinline__ char f2e4m3(float f) {
    unsigned p = __builtin_amdgcn_cvt_pk_fp8_f32(f, f, 0, false);
    return (char)(p & 0xff);
}

// supertile swizzle: bands of 16 row-tiles so concurrent blocks share A/B panels in L2/LLC
__device__ __forceinline__ void tile_coords(int bid, int tn, int& bm, int& bn) {
    const int SUP = 16;
    int per = SUP * tn;
    int band = bid / per, r = bid % per;
    bm = band * SUP + (r % SUP);
    bn = r / SUP;
}

// ---------------- bf16 GEMM core (k_proj) ----------------
__device__ __forceinline__ void gemm_core(const short* __restrict__ A,
                                          const short* __restrict__ B,
                                          int K, int m0, int n0,
                                          short* smem, v4f (&acc)[4][4])
{
    short* lsA = smem;            // 128*64 shorts
    short* lsB = smem + 8192;
    const int tid  = threadIdx.x;
    const int wave = tid >> 6, lane = tid & 63;
    const int l15 = lane & 15, l4 = lane >> 4;
    const int wm = (wave >> 1) << 6, wn = (wave & 1) << 6;

#pragma unroll
    for (int i = 0; i < 4; i++)
#pragma unroll
        for (int j = 0; j < 4; j++) acc[i][j] = (v4f)(0.0f);

    const int srow = lane >> 3;
    const int g    = (lane & 7) ^ srow;

    for (int k0 = 0; k0 < K; k0 += 64) {
#pragma unroll
        for (int i = 0; i < 4; i++) {
            int ci  = wave * 4 + i;
            int row = ci * 8 + srow;
            const short* ga = A + (size_t)(m0 + row) * K + k0 + g * 8;
            const short* gb = B + (size_t)(n0 + row) * K + k0 + g * 8;
            __builtin_amdgcn_global_load_lds((gp_t)ga, (lp_t)(lsA + ci * 512), 16, 0, 0);
            __builtin_amdgcn_global_load_lds((gp_t)gb, (lp_t)(lsB + ci * 512), 16, 0, 0);
        }
        __syncthreads();
#pragma unroll
        for (int kk = 0; kk < 64; kk += 32) {
            v8s af[4], bf[4];
#pragma unroll
            for (int t = 0; t < 4; t++) {
                int ra = wm + t * 16 + l15;
                int ca = ((kk >> 3) + l4) ^ (ra & 7);
                af[t] = *(const v8s*)(lsA + ra * 64 + ca * 8);
                int rb = wn + t * 16 + l15;
                int cb = ((kk >> 3) + l4) ^ (rb & 7);
                bf[t] = *(const v8s*)(lsB + rb * 64 + cb * 8);
            }
#pragma unroll
            for (int i = 0; i < 4; i++)
#pragma unroll
                for (int j = 0; j < 4; j++)
                    acc[i][j] = __builtin_amdgcn_mfma_f32_16x16x32_bf16(af[i], bf[j], acc[i][j], 0, 0, 0);
        }
        __syncthreads();
    }
}

// ---------------- fp8 GEMM core (k_score) ----------------
__device__ __forceinline__ void gemm_core_fp8(const char* __restrict__ A,
                                              const char* __restrict__ B,
                                              int K, int m0, int n0,
                                              char* smem, v4f (&acc)[4][4])
{
    char* lsA = smem;             // 128 rows * 128 B
    char* lsB = smem + 16384;
    const int tid  = threadIdx.x;
    const int wave = tid >> 6, lane = tid & 63;
    const int l15 = lane & 15, l4 = lane >> 4;
    const int wm = (wave >> 1) << 6, wn = (wave & 1) << 6;

#pragma unroll
    for (int i = 0; i < 4; i++)
#pragma unroll
        for (int j = 0; j < 4; j++) acc[i][j] = (v4f)(0.0f);

    const int srow = lane >> 3;
    const int g    = (lane & 7) ^ srow;

    for (int k0 = 0; k0 < K; k0 += 128) {
#pragma unroll
        for (int i = 0; i < 4; i++) {
            int ci  = wave * 4 + i;
            int row = ci * 8 + srow;
            const char* ga = A + (size_t)(m0 + row) * K + k0 + g * 16;
            const char* gb = B + (size_t)(n0 + row) * K + k0 + g * 16;
            __builtin_amdgcn_global_load_lds((gp_t)ga, (lp_t)(lsA + ci * 1024), 16, 0, 0);
            __builtin_amdgcn_global_load_lds((gp_t)gb, (lp_t)(lsB + ci * 1024), 16, 0, 0);
        }
        __syncthreads();
#pragma unroll
        for (int kk = 0; kk < 128; kk += 32) {
            long af[4], bq[4];
            const int cbase = (kk >> 4) + (l4 >> 1);
            const int half  = (l4 & 1) * 8;
#pragma unroll
            for (int t = 0; t < 4; t++) {
                int ra = wm + t * 16 + l15;
                int ca = cbase ^ (ra & 7);
                af[t] = *(const long*)(lsA + ra * 128 + ca * 16 + half);
                int rb = wn + t * 16 + l15;
                int cb = cbase ^ (rb & 7);
                bq[t] = *(const long*)(lsB + rb * 128 + cb * 16 + half);
            }
#pragma unroll
            for (int i = 0; i < 4; i++)
#pragma unroll
                for (int j = 0; j < 4; j++)
                    acc[i][j] = __builtin_amdgcn_mfma_f32_16x16x32_fp8_fp8(af[i], bq[j], acc[i][j], 0, 0, 0);
        }
        __syncthreads();
    }
}

// ---------------- MX fp8 GEMM core v1 (k_out; R4-best) ----------------
__device__ __forceinline__ void gemm_core_mx(const char* __restrict__ A,
                                             const char* __restrict__ B,
                                             int K, int m0, int n0,
                                             char* smem, v4f (&acc)[4][4])
{
    char* lsA = smem;             // 128 rows * 128 B
    char* lsB = smem + 16384;
    const int tid  = threadIdx.x;
    const int wave = tid >> 6, lane = tid & 63;
    const int l15 = lane & 15, l4 = lane >> 4;
    const int wm = (wave >> 1) << 6, wn = (wave & 1) << 6;

#pragma unroll
    for (int i = 0; i < 4; i++)
#pragma unroll
        for (int j = 0; j < 4; j++) acc[i][j] = (v4f)(0.0f);

    const int srow = lane >> 3;
    const int g    = (lane & 7) ^ srow;

    for (int k0 = 0; k0 < K; k0 += 128) {
#pragma unroll
        for (int i = 0; i < 4; i++) {
            int ci  = wave * 4 + i;
            int row = ci * 8 + srow;
            const char* ga = A + (size_t)(m0 + row) * K + k0 + g * 16;
            const char* gb = B + (size_t)(n0 + row) * K + k0 + g * 16;
            __builtin_amdgcn_global_load_lds((gp_t)ga, (lp_t)(lsA + ci * 1024), 16, 0, 0);
            __builtin_amdgcn_global_load_lds((gp_t)gb, (lp_t)(lsB + ci * 1024), 16, 0, 0);
        }
        __syncthreads();
        v8i af[4], bq[4];
#pragma unroll
        for (int t = 0; t < 4; t++) {
            int ra = wm + t * 16 + l15;
            int a0 = (2 * l4) ^ (ra & 7), a1 = (2 * l4 + 1) ^ (ra & 7);
            v4i lo = *(const v4i*)(lsA + ra * 128 + a0 * 16);
            v4i hi = *(const v4i*)(lsA + ra * 128 + a1 * 16);
            af[t][0] = lo[0]; af[t][1] = lo[1]; af[t][2] = lo[2]; af[t][3] = lo[3];
            af[t][4] = hi[0]; af[t][5] = hi[1]; af[t][6] = hi[2]; af[t][7] = hi[3];
            int rb = wn + t * 16 + l15;
            int b0 = (2 * l4) ^ (rb & 7), b1 = (2 * l4 + 1) ^ (rb & 7);
            v4i blo = *(const v4i*)(lsB + rb * 128 + b0 * 16);
            v4i bhi = *(const v4i*)(lsB + rb * 128 + b1 * 16);
            bq[t][0] = blo[0]; bq[t][1] = blo[1]; bq[t][2] = blo[2]; bq[t][3] = blo[3];
            bq[t][4] = bhi[0]; bq[t][5] = bhi[1]; bq[t][6] = bhi[2]; bq[t][7] = bhi[3];
        }
#pragma unroll
        for (int i = 0; i < 4; i++)
#pragma unroll
            for (int j = 0; j < 4; j++)
                acc[i][j] = __builtin_amdgcn_mfma_scale_f32_16x16x128_f8f6f4(
                    af[i], bq[j], acc[i][j], 0, 0,
                    0, 0x7f7f7f7f, 0, 0x7f7f7f7f);   // e8m0 0x7f = 1.0
        __syncthreads();
    }
}

// ---------------- fused prep kernel ----------------
// blocks [0,2048): x -> bf16 xb; m = x.Wm + b; em = exp(m). Block 0 zeroes stats.
// blocks [2048,2816): weight transpose+cvt (was cvt_w, dim3(16,16,3) flattened).
__global__ void prep(const float* __restrict__ x, const float* __restrict__ wv,
                     const float* __restrict__ bp, short* __restrict__ xb,
                     float* __restrict__ em,
                     const float* __restrict__ Wq, const float* __restrict__ Wk,
                     const float* __restrict__ Wg, short* __restrict__ wbt,
                     float* __restrict__ zero_base) {
    __shared__ float t[64][68];
    int bid = blockIdx.x, tid = threadIdx.x;
    if (bid < 2048) {
        if (bid == 0) {
            // zero qsum(1024) + gsum(1024) + lrow(8192)
            for (int i = tid; i < 2 * DD + NT; i += 256) zero_base[i] = 0.f;
        }
        int wv_id = tid >> 6;
        int row = bid * 4 + wv_id;
        int lane = tid & 63;
        const float* xr = x + (size_t)row * DD;
        short* xbr = xb + (size_t)row * DD;
        float s = 0.f;
        for (int c = lane * 4; c < DD; c += 256) {
            float4 a = *(const float4*)(xr + c);
            float4 b = *(const float4*)(wv + c);
            s = fmaf(a.x, b.x, s); s = fmaf(a.y, b.y, s);
            s = fmaf(a.z, b.z, s); s = fmaf(a.w, b.w, s);
            short4 o;
            o.x = f2b(a.x); o.y = f2b(a.y); o.z = f2b(a.z); o.w = f2b(a.w);
            *(short4*)(xbr + c) = o;
        }
        for (int o = 32; o; o >>= 1) s += __shfl_down(s, o);
        if (lane == 0) em[row] = __expf(s + bp[0]);
    } else {
        int idx = bid - 2048;
        int bz = idx >> 8, rem = idx & 255;
        const float* W = bz == 0 ? Wq : (bz == 1 ? Wk : Wg);
        int k0 = (rem & 15) * 64, n0 = (rem >> 4) * 64;
        int tr = tid >> 4, tc = tid & 15;
#pragma unroll
        for (int p = 0; p < 4; p++) {
            int r = p * 16 + tr;
            float4 v = *(const float4*)(W + (size_t)(k0 + r) * DD + n0 + tc * 4);
            t[r][tc * 4 + 0] = v.x; t[r][tc * 4 + 1] = v.y;
            t[r][tc * 4 + 2] = v.z; t[r][tc * 4 + 3] = v.w;
        }
        __syncthreads();
#pragma unroll
        for (int p = 0; p < 4; p++) {
            int rr = p * 16 + tr;
            short4 s;
            s.x = f2b(t[tc * 4 + 0][rr]); s.y = f2b(t[tc * 4 + 1][rr]);
            s.z = f2b(t[tc * 4 + 2][rr]); s.w = f2b(t[tc * 4 + 3][rr]);
            *(short4*)(wbt + (size_t)(bz * DD + n0 + rr) * DD + k0 + tc * 4) = s;
        }
    }
}

// beta[j] = (c/NT) * sum_d qsum[d] * k8[j][d]; block 2048 reduces em -> gden
__global__ void beta_gemv(const char* __restrict__ k8, const float* __restrict__ qsum,
                          const float* __restrict__ cp, float* __restrict__ beta,
                          const float* __restrict__ em, float* __restrict__ gden) {
    int tid = threadIdx.x, lane = tid & 63;
    if (blockIdx.x == 2048) {
        __shared__ float sr[4];
        float s = 0.f;
        for (int i = tid; i < NT; i += 256) s += em[i];
        for (int o = 32; o; o >>= 1) s += __shfl_xor(s, o);
        if (lane == 0) sr[tid >> 6] = s;
        __syncthreads();
        if (tid == 0) gden[0] = sr[0] + sr[1] + sr[2] + sr[3];
        return;
    }
    int row = blockIdx.x * 4 + (tid >> 6);
    v4i kv = *(const v4i*)(k8 + (size_t)row * DD + lane * 16);
    const float* qs = qsum + lane * 16;
    float s = 0.f;
#pragma unroll
    for (int w = 0; w < 4; w++) {
        float4 qv = *(const float4*)(qs + w * 4);
        int word = kv[w];
        s = fmaf(__builtin_amdgcn_cvt_f32_fp8(word, 0), qv.x, s);
        s = fmaf(__builtin_amdgcn_cvt_f32_fp8(word, 1), qv.y, s);
        s = fmaf(__builtin_amdgcn_cvt_f32_fp8(word, 2), qv.z, s);
        s = fmaf(__builtin_amdgcn_cvt_f32_fp8(word, 3), qv.w, s);
    }
    for (int o = 32; o; o >>= 1) s += __shfl_down(s, o);
    if (lane == 0) beta[row] = s * cp[0] / (float)NT;
}

// ---------------- GEMM kernels ----------------

// K1: C = x @ [Wq|Wk|Wg]  (M=8192, N=3072, K=1024), bf16 MFMA, fp8 outputs
__global__ __launch_bounds__(256, 2) void k_proj(
        const short* __restrict__ xb, const short* __restrict__ wbt,
        char* __restrict__ q8, char* __restrict__ k8, char* __restrict__ gbt,
        float* __restrict__ qsum, float* __restrict__ gsum) {
    __shared__ __align__(16) short smem[16384];
    int bm, bn; tile_coords(blockIdx.x, 24, bm, bn);
    int m0 = bm * 128, n0 = bn * 128;
    v4f acc[4][4];
    gemm_core(xb, wbt, DD, m0, n0, smem, acc);

    const int tid = threadIdx.x, wave = tid >> 6, lane = tid & 63;
    const int l15 = lane & 15, l4 = lane >> 4;
    const int wm = (wave >> 1) << 6, wn = (wave & 1) << 6;
    int sec = n0 >> 10;            // 0=q 1=k 2=g
    int nloc = n0 & (DD - 1);

    if (sec < 2) {
        char* dst = sec ? k8 : q8;
        float cs[4] = {0.f, 0.f, 0.f, 0.f};
#pragma unroll
        for (int i = 0; i < 4; i++)
#pragma unroll
            for (int j = 0; j < 4; j++)
#pragma unroll
                for (int v = 0; v < 4; v++) {
                    int row = m0 + wm + i * 16 + l4 * 4 + v;
                    int col = nloc + wn + j * 16 + l15;
                    dst[(size_t)row * DD + col] = f2e4m3(acc[i][j][v]);
                    cs[j] += acc[i][j][v];
                }
        if (sec == 0)
#pragma unroll
            for (int j = 0; j < 4; j++)
                atomicAdd(&qsum[nloc + wn + j * 16 + l15], cs[j]);
    } else {
        // g tile -> transposed fp8 store gbt[d][i] via LDS bounce
        char* sc = (char*)smem;
        float cs[4] = {0.f, 0.f, 0.f, 0.f};
#pragma unroll
        for (int i = 0; i < 4; i++)
#pragma unroll
            for (int j = 0; j < 4; j++)
#pragma unroll
                for (int v = 0; v < 4; v++) {
                    int lr = wn + j * 16 + l15;            // local d
                    int lc = wm + i * 16 + l4 * 4 + v;     // local token
                    sc[lr * 144 + lc] = f2e4m3(acc[i][j][v]);
                    cs[j] += acc[i][j][v];
                }
        __syncthreads();
#pragma unroll
        for (int it = 0; it < 4; it++) {
            int c = it * 256 + tid;
            int dr = c >> 3, cm = (c & 7) * 16;
            int4 vv = *(const int4*)(sc + dr * 144 + cm);
            *(int4*)(gbt + (size_t)(nloc + dr) * NT + m0 + cm) = vv;
        }
#pragma unroll
        for (int j = 0; j < 4; j++)
            atomicAdd(&gsum[nloc + wn + j * 16 + l15], cs[j]);
    }
}

// K3: E = exp(c*q@k^T - beta_j) e4m3, l += rowsum(E)
__global__ __launch_bounds__(256, 2) void k_score(
        const char* __restrict__ q8, const char* __restrict__ k8,
        char* __restrict__ E, float* __restrict__ l, const float* __restrict__ cptr,
        const float* __restrict__ beta) {
    __shared__ __align__(16) char smem[32768];
    int bm, bn; tile_coords(blockIdx.x, 64, bm, bn);
    int m0 = bm * 128, n0 = bn * 128;
    v4f acc[4][4];
    gemm_core_fp8(q8, k8, DD, m0, n0, smem, acc);

    const float cv = cptr[0];
    const int tid = threadIdx.x, wave = tid >> 6, lane = tid & 63;
    const int l15 = lane & 15, l4 = lane >> 4;
    const int wm = (wave >> 1) << 6, wn = (wave & 1) << 6;
    float bj[4];
#pragma unroll
    for (int j = 0; j < 4; j++) bj[j] = beta[n0 + wn + j * 16 + l15];
#pragma unroll
    for (int i = 0; i < 4; i++)
#pragma unroll
        for (int v = 0; v < 4; v++) {
            int row = m0 + wm + i * 16 + l4 * 4 + v;
            float rsum = 0.f;
#pragma unroll
            for (int j = 0; j < 4; j++) {
                float e = __expf(cv * acc[i][j][v] - bj[j]);
                E[(size_t)row * NT + (n0 + wn + j * 16 + l15)] = f2e4m3(e);
                rsum += e;
            }
#pragma unroll
            for (int o = 1; o < 16; o <<= 1) rsum += __shfl_xor(rsum, o);
            if (l15 == 0) atomicAdd(&l[row], rsum);
        }
}

// K4: out = (E @ g)/l + (em/gden)*gsum + x
__global__ __launch_bounds__(256, 2) void k_out(
        const char* __restrict__ E, const char* __restrict__ gbt,
        const float* __restrict__ l, const float* __restrict__ em,
        const float* __restrict__ gden, const float* __restrict__ gsum,
        const float* __restrict__ x, float* __restrict__ out) {
    __shared__ __align__(16) char smem[32768];
    int bm, bn; tile_coords(blockIdx.x, 8, bm, bn);
    int m0 = bm * 128, n0 = bn * 128;
    v4f acc[4][4];
    gemm_core_mx(E, gbt, NT, m0, n0, smem, acc);

    const float ginv = 1.f / gden[0];
    const int tid = threadIdx.x, wave = tid >> 6, lane = tid & 63;
    const int l15 = lane & 15, l4 = lane >> 4;
    const int wm = (wave >> 1) << 6, wn = (wave & 1) << 6;
#pragma unroll
    for (int i = 0; i < 4; i++)
#pragma unroll
        for (int v = 0; v < 4; v++) {
            int row = m0 + wm + i * 16 + l4 * 4 + v;
            float inv = 1.f / l[row];
            float gv  = em[row] * ginv;
#pragma unroll
            for (int j = 0; j < 4; j++) {
                int col = n0 + wn + j * 16 + l15;
                out[(size_t)row * DD + col] =
                    acc[i][j][v] * inv + gv * gsum[col] + x[(size_t)row * DD + col];
            }
        }
}

// ---------------- launch ----------------

extern "C" void kernel_launch(void* const* d_in, const int* in_sizes, int n_in,
                              void* d_out, int out_size, void* d_ws, size_t ws_size,
                              hipStream_t stream) {
    const float* x  = (const float*)d_in[0];
    const float* Wq = (const float*)d_in[1];
    const float* Wk = (const float*)d_in[2];
    const float* Wg = (const float*)d_in[3];
    const float* Wm = (const float*)d_in[4];
    const float* Wb = (const float*)d_in[5];
    const float* cp = (const float*)d_in[6];
    float* out = (float*)d_out;

    char* w = (char*)d_ws;
    size_t off = 0;
    auto alloc = [&](size_t bytes) -> void* {
        void* p = w + off;
        off += (bytes + 255) & ~(size_t)255;
        return p;
    };
    char*  q8    = (char*)alloc((size_t)NT * DD);           // 8 MB fp8 q_hat
    char*  k8    = (char*)alloc((size_t)NT * DD);           // 8 MB fp8 k_hat
    char*  gbt   = (char*)alloc((size_t)DD * NT);           // 8 MB fp8 g^T
    short* wbt   = (short*)alloc((size_t)3 * DD * DD * 2);  // 6 MB
    short* xb    = (short*)alloc((size_t)NT * DD * 2);      // 16 MB
    char*  E     = (char*)alloc((size_t)NT * NT);           // 64 MB fp8
    float* stats = (float*)alloc((2 * DD + 3 * NT + 1) * 4);
    float* qsum = stats;
    float* gsum = stats + DD;
    float* lrow = stats + 2 * DD;
    float* gden = lrow + NT;
    float* em   = gden + 1;
    float* beta = em + NT;
    if (off > ws_size) return;

    // prep zeroes [qsum, gsum, lrow] (2*DD+NT floats); gden/em/beta are
    // plain-written downstream, no zeroing needed.
    prep<<<2048 + 768, 256, 0, stream>>>(x, Wm, Wb, xb, em, Wq, Wk, Wg, wbt, stats);
    k_proj<<<64 * 24, 256, 0, stream>>>(xb, wbt, q8, k8, gbt, qsum, gsum);
    beta_gemv<<<2049, 256, 0, stream>>>(k8, qsum, cp, beta, em, gden);
    k_score<<<64 * 64, 256, 0, stream>>>(q8, k8, E, lrow, cp, beta);
    k_out<<<64 * 8, 256, 0, stream>>>(E, gbt, lrow, em, gden, gsum, x, out);
}

// Round 7
// 370.291 us; speedup vs baseline: 1.1820x; 1.0998x over previous
//
#include <hip/hip_runtime.h>
#include <math.h>

// N=8192 tokens, D=1024. All inputs fp32.
// out = (E@g)/l + gate*colsum(g) + x
// E = exp(c*q_hat@k_hat^T - beta_j), beta_j = c*mean(q_hat)·k_hat_j  (row-uniform
// centering terms cancel in E/rowsum(E)); gate = exp(m)/sum(exp(m)), no max needed.
// R7: k_proj ported to the fp8 core (x8, W8T*16, BK=128 bytes, 8 staging iters;
// epilogue un-scales by 1/16). k_score fp8 core, k_out MX v1 — both frozen.

#define NT 8192
#define DD 1024

typedef float v4f __attribute__((ext_vector_type(4)));
typedef short v8s __attribute__((ext_vector_type(8)));
typedef int   v4i __attribute__((ext_vector_type(4)));
typedef int   v8i __attribute__((ext_vector_type(8)));

typedef const __attribute__((address_space(1))) void* gp_t;
typedef __attribute__((address_space(3))) void* lp_t;

__device__ __forceinline__ short f2b(float f) {
    unsigned u = __float_as_uint(f);
    return (short)((u + 0x7fffu + ((u >> 16) & 1u)) >> 16);   // RNE
}
__device__ __forceinline__ char f2e4m3(float f) {
    unsigned p = __builtin_amdgcn_cvt_pk_fp8_f32(f, f, 0, false);
    return (char)(p & 0xff);
}

// supertile swizzle: bands of 16 row-tiles so concurrent blocks share A/B panels in L2/LLC
__device__ __forceinline__ void tile_coords(int bid, int tn, int& bm, int& bn) {
    const int SUP = 16;
    int per = SUP * tn;
    int band = bid / per, r = bid % per;
    bm = band * SUP + (r % SUP);
    bn = r / SUP;
}

// ---------------- fp8 GEMM core (k_proj, k_score) ----------------
// A: [M x K] e4m3 row-major (K in BYTES), B: [N x K] e4m3 row-major.
// BK=128 bytes; 4 MFMA k-steps of 32 per staging iter.
__device__ __forceinline__ void gemm_core_fp8(const char* __restrict__ A,
                                              const char* __restrict__ B,
                                              int K, int m0, int n0,
                                              char* smem, v4f (&acc)[4][4])
{
    char* lsA = smem;             // 128 rows * 128 B
    char* lsB = smem + 16384;
    const int tid  = threadIdx.x;
    const int wave = tid >> 6, lane = tid & 63;
    const int l15 = lane & 15, l4 = lane >> 4;
    const int wm = (wave >> 1) << 6, wn = (wave & 1) << 6;

#pragma unroll
    for (int i = 0; i < 4; i++)
#pragma unroll
        for (int j = 0; j < 4; j++) acc[i][j] = (v4f)(0.0f);

    const int srow = lane >> 3;
    const int g    = (lane & 7) ^ srow;

    for (int k0 = 0; k0 < K; k0 += 128) {
#pragma unroll
        for (int i = 0; i < 4; i++) {
            int ci  = wave * 4 + i;
            int row = ci * 8 + srow;
            const char* ga = A + (size_t)(m0 + row) * K + k0 + g * 16;
            const char* gb = B + (size_t)(n0 + row) * K + k0 + g * 16;
            __builtin_amdgcn_global_load_lds((gp_t)ga, (lp_t)(lsA + ci * 1024), 16, 0, 0);
            __builtin_amdgcn_global_load_lds((gp_t)gb, (lp_t)(lsB + ci * 1024), 16, 0, 0);
        }
        __syncthreads();
#pragma unroll
        for (int kk = 0; kk < 128; kk += 32) {
            long af[4], bq[4];
            const int cbase = (kk >> 4) + (l4 >> 1);
            const int half  = (l4 & 1) * 8;
#pragma unroll
            for (int t = 0; t < 4; t++) {
                int ra = wm + t * 16 + l15;
                int ca = cbase ^ (ra & 7);
                af[t] = *(const long*)(lsA + ra * 128 + ca * 16 + half);
                int rb = wn + t * 16 + l15;
                int cb = cbase ^ (rb & 7);
                bq[t] = *(const long*)(lsB + rb * 128 + cb * 16 + half);
            }
#pragma unroll
            for (int i = 0; i < 4; i++)
#pragma unroll
                for (int j = 0; j < 4; j++)
                    acc[i][j] = __builtin_amdgcn_mfma_f32_16x16x32_fp8_fp8(af[i], bq[j], acc[i][j], 0, 0, 0);
        }
        __syncthreads();
    }
}

// ---------------- MX fp8 GEMM core v1 (k_out) ----------------
__device__ __forceinline__ void gemm_core_mx(const char* __restrict__ A,
                                             const char* __restrict__ B,
                                             int K, int m0, int n0,
                                             char* smem, v4f (&acc)[4][4])
{
    char* lsA = smem;             // 128 rows * 128 B
    char* lsB = smem + 16384;
    const int tid  = threadIdx.x;
    const int wave = tid >> 6, lane = tid & 63;
    const int l15 = lane & 15, l4 = lane >> 4;
    const int wm = (wave >> 1) << 6, wn = (wave & 1) << 6;

#pragma unroll
    for (int i = 0; i < 4; i++)
#pragma unroll
        for (int j = 0; j < 4; j++) acc[i][j] = (v4f)(0.0f);

    const int srow = lane >> 3;
    const int g    = (lane & 7) ^ srow;

    for (int k0 = 0; k0 < K; k0 += 128) {
#pragma unroll
        for (int i = 0; i < 4; i++) {
            int ci  = wave * 4 + i;
            int row = ci * 8 + srow;
            const char* ga = A + (size_t)(m0 + row) * K + k0 + g * 16;
            const char* gb = B + (size_t)(n0 + row) * K + k0 + g * 16;
            __builtin_amdgcn_global_load_lds((gp_t)ga, (lp_t)(lsA + ci * 1024), 16, 0, 0);
            __builtin_amdgcn_global_load_lds((gp_t)gb, (lp_t)(lsB + ci * 1024), 16, 0, 0);
        }
        __syncthreads();
        v8i af[4], bq[4];
#pragma unroll
        for (int t = 0; t < 4; t++) {
            int ra = wm + t * 16 + l15;
            int a0 = (2 * l4) ^ (ra & 7), a1 = (2 * l4 + 1) ^ (ra & 7);
            v4i lo = *(const v4i*)(lsA + ra * 128 + a0 * 16);
            v4i hi = *(const v4i*)(lsA + ra * 128 + a1 * 16);
            af[t][0] = lo[0]; af[t][1] = lo[1]; af[t][2] = lo[2]; af[t][3] = lo[3];
            af[t][4] = hi[0]; af[t][5] = hi[1]; af[t][6] = hi[2]; af[t][7] = hi[3];
            int rb = wn + t * 16 + l15;
            int b0 = (2 * l4) ^ (rb & 7), b1 = (2 * l4 + 1) ^ (rb & 7);
            v4i blo = *(const v4i*)(lsB + rb * 128 + b0 * 16);
            v4i bhi = *(const v4i*)(lsB + rb * 128 + b1 * 16);
            bq[t][0] = blo[0]; bq[t][1] = blo[1]; bq[t][2] = blo[2]; bq[t][3] = blo[3];
            bq[t][4] = bhi[0]; bq[t][5] = bhi[1]; bq[t][6] = bhi[2]; bq[t][7] = bhi[3];
        }
#pragma unroll
        for (int i = 0; i < 4; i++)
#pragma unroll
            for (int j = 0; j < 4; j++)
                acc[i][j] = __builtin_amdgcn_mfma_scale_f32_16x16x128_f8f6f4(
                    af[i], bq[j], acc[i][j], 0, 0,
                    0, 0x7f7f7f7f, 0, 0x7f7f7f7f);   // e8m0 0x7f = 1.0
        __syncthreads();
    }
}

// ---------------- fused prep kernel ----------------
// blocks [0,2048): x -> e4m3 x8; m = x.Wm + b; em = exp(m). Block 0 zeroes stats.
// blocks [2048,2816): weight transpose + *16 + e4m3 cvt.
__global__ void prep(const float* __restrict__ x, const float* __restrict__ wv,
                     const float* __restrict__ bp, char* __restrict__ x8,
                     float* __restrict__ em,
                     const float* __restrict__ Wq, const float* __restrict__ Wk,
                     const float* __restrict__ Wg, char* __restrict__ w8t,
                     float* __restrict__ zero_base) {
    __shared__ float t[64][68];
    int bid = blockIdx.x, tid = threadIdx.x;
    if (bid < 2048) {
        if (bid == 0) {
            // zero qsum(1024) + gsum(1024) + lrow(8192)
            for (int i = tid; i < 2 * DD + NT; i += 256) zero_base[i] = 0.f;
        }
        int wv_id = tid >> 6;
        int row = bid * 4 + wv_id;
        int lane = tid & 63;
        const float* xr = x + (size_t)row * DD;
        char* x8r = x8 + (size_t)row * DD;
        float s = 0.f;
        for (int c = lane * 4; c < DD; c += 256) {
            float4 a = *(const float4*)(xr + c);
            float4 b = *(const float4*)(wv + c);
            s = fmaf(a.x, b.x, s); s = fmaf(a.y, b.y, s);
            s = fmaf(a.z, b.z, s); s = fmaf(a.w, b.w, s);
            unsigned p = __builtin_amdgcn_cvt_pk_fp8_f32(a.x, a.y, 0, false);
            p = __builtin_amdgcn_cvt_pk_fp8_f32(a.z, a.w, p, true);
            *(int*)(x8r + c) = (int)p;
        }
        for (int o = 32; o; o >>= 1) s += __shfl_down(s, o);
        if (lane == 0) em[row] = __expf(s + bp[0]);
    } else {
        int idx = bid - 2048;
        int bz = idx >> 8, rem = idx & 255;
        const float* W = bz == 0 ? Wq : (bz == 1 ? Wk : Wg);
        int k0 = (rem & 15) * 64, n0 = (rem >> 4) * 64;
        int tr = tid >> 4, tc = tid & 15;
#pragma unroll
        for (int p = 0; p < 4; p++) {
            int r = p * 16 + tr;
            float4 v = *(const float4*)(W + (size_t)(k0 + r) * DD + n0 + tc * 4);
            t[r][tc * 4 + 0] = v.x; t[r][tc * 4 + 1] = v.y;
            t[r][tc * 4 + 2] = v.z; t[r][tc * 4 + 3] = v.w;
        }
        __syncthreads();
#pragma unroll
        for (int p = 0; p < 4; p++) {
            int rr = p * 16 + tr;   // local n
            // w8t = e4m3(16 * W^T)  (x16 keeps ~N(0,1/32) weights in e4m3 sweet spot)
            unsigned pk = __builtin_amdgcn_cvt_pk_fp8_f32(
                16.f * t[tc * 4 + 0][rr], 16.f * t[tc * 4 + 1][rr], 0, false);
            pk = __builtin_amdgcn_cvt_pk_fp8_f32(
                16.f * t[tc * 4 + 2][rr], 16.f * t[tc * 4 + 3][rr], pk, true);
            *(int*)(w8t + (size_t)(bz * DD + n0 + rr) * DD + k0 + tc * 4) = (int)pk;
        }
    }
}

// beta[j] = (c/NT) * sum_d qsum[d] * k8[j][d]; block 2048 reduces em -> gden
__global__ void beta_gemv(const char* __restrict__ k8, const float* __restrict__ qsum,
                          const float* __restrict__ cp, float* __restrict__ beta,
                          const float* __restrict__ em, float* __restrict__ gden) {
    int tid = threadIdx.x, lane = tid & 63;
    if (blockIdx.x == 2048) {
        __shared__ float sr[4];
        float s = 0.f;
        for (int i = tid; i < NT; i += 256) s += em[i];
        for (int o = 32; o; o >>= 1) s += __shfl_xor(s, o);
        if (lane == 0) sr[tid >> 6] = s;
        __syncthreads();
        if (tid == 0) gden[0] = sr[0] + sr[1] + sr[2] + sr[3];
        return;
    }
    int row = blockIdx.x * 4 + (tid >> 6);
    v4i kv = *(const v4i*)(k8 + (size_t)row * DD + lane * 16);
    const float* qs = qsum + lane * 16;
    float s = 0.f;
#pragma unroll
    for (int w = 0; w < 4; w++) {
        float4 qv = *(const float4*)(qs + w * 4);
        int word = kv[w];
        s = fmaf(__builtin_amdgcn_cvt_f32_fp8(word, 0), qv.x, s);
        s = fmaf(__builtin_amdgcn_cvt_f32_fp8(word, 1), qv.y, s);
        s = fmaf(__builtin_amdgcn_cvt_f32_fp8(word, 2), qv.z, s);
        s = fmaf(__builtin_amdgcn_cvt_f32_fp8(word, 3), qv.w, s);
    }
    for (int o = 32; o; o >>= 1) s += __shfl_down(s, o);
    if (lane == 0) beta[row] = s * cp[0] / (float)NT;
}

// ---------------- GEMM kernels ----------------

// K1: C = (1/16) * x8 @ w8t^T  (M=8192, N=3072, K=1024 bytes), fp8 MFMA
__global__ __launch_bounds__(256, 2) void k_proj(
        const char* __restrict__ x8, const char* __restrict__ w8t,
        char* __restrict__ q8, char* __restrict__ k8, char* __restrict__ gbt,
        float* __restrict__ qsum, float* __restrict__ gsum) {
    __shared__ __align__(16) char smem[32768];
    int bm, bn; tile_coords(blockIdx.x, 24, bm, bn);
    int m0 = bm * 128, n0 = bn * 128;
    v4f acc[4][4];
    gemm_core_fp8(x8, w8t, DD, m0, n0, smem, acc);

    const int tid = threadIdx.x, wave = tid >> 6, lane = tid & 63;
    const int l15 = lane & 15, l4 = lane >> 4;
    const int wm = (wave >> 1) << 6, wn = (wave & 1) << 6;
    int sec = n0 >> 10;            // 0=q 1=k 2=g
    int nloc = n0 & (DD - 1);
    const float WS = 0.0625f;      // undo the *16 weight scale

    if (sec < 2) {
        char* dst = sec ? k8 : q8;
        float cs[4] = {0.f, 0.f, 0.f, 0.f};
#pragma unroll
        for (int i = 0; i < 4; i++)
#pragma unroll
            for (int j = 0; j < 4; j++)
#pragma unroll
                for (int v = 0; v < 4; v++) {
                    int row = m0 + wm + i * 16 + l4 * 4 + v;
                    int col = nloc + wn + j * 16 + l15;
                    float av = acc[i][j][v] * WS;
                    dst[(size_t)row * DD + col] = f2e4m3(av);
                    cs[j] += av;
                }
        if (sec == 0)
#pragma unroll
            for (int j = 0; j < 4; j++)
                atomicAdd(&qsum[nloc + wn + j * 16 + l15], cs[j]);
    } else {
        // g tile -> transposed fp8 store gbt[d][i] via LDS bounce
        char* sc = smem;
        float cs[4] = {0.f, 0.f, 0.f, 0.f};
#pragma unroll
        for (int i = 0; i < 4; i++)
#pragma unroll
            for (int j = 0; j < 4; j++)
#pragma unroll
                for (int v = 0; v < 4; v++) {
                    int lr = wn + j * 16 + l15;            // local d
                    int lc = wm + i * 16 + l4 * 4 + v;     // local token
                    float av = acc[i][j][v] * WS;
                    sc[lr * 144 + lc] = f2e4m3(av);
                    cs[j] += av;
                }
        __syncthreads();
#pragma unroll
        for (int it = 0; it < 4; it++) {
            int c = it * 256 + tid;
            int dr = c >> 3, cm = (c & 7) * 16;
            int4 vv = *(const int4*)(sc + dr * 144 + cm);
            *(int4*)(gbt + (size_t)(nloc + dr) * NT + m0 + cm) = vv;
        }
#pragma unroll
        for (int j = 0; j < 4; j++)
            atomicAdd(&gsum[nloc + wn + j * 16 + l15], cs[j]);
    }
}

// K3: E = exp(c*q@k^T - beta_j) e4m3, l += rowsum(E)
__global__ __launch_bounds__(256, 2) void k_score(
        const char* __restrict__ q8, const char* __restrict__ k8,
        char* __restrict__ E, float* __restrict__ l, const float* __restrict__ cptr,
        const float* __restrict__ beta) {
    __shared__ __align__(16) char smem[32768];
    int bm, bn; tile_coords(blockIdx.x, 64, bm, bn);
    int m0 = bm * 128, n0 = bn * 128;
    v4f acc[4][4];
    gemm_core_fp8(q8, k8, DD, m0, n0, smem, acc);

    const float cv = cptr[0];
    const int tid = threadIdx.x, wave = tid >> 6, lane = tid & 63;
    const int l15 = lane & 15, l4 = lane >> 4;
    const int wm = (wave >> 1) << 6, wn = (wave & 1) << 6;
    float bj[4];
#pragma unroll
    for (int j = 0; j < 4; j++) bj[j] = beta[n0 + wn + j * 16 + l15];
#pragma unroll
    for (int i = 0; i < 4; i++)
#pragma unroll
        for (int v = 0; v < 4; v++) {
            int row = m0 + wm + i * 16 + l4 * 4 + v;
            float rsum = 0.f;
#pragma unroll
            for (int j = 0; j < 4; j++) {
                float e = __expf(cv * acc[i][j][v] - bj[j]);
                E[(size_t)row * NT + (n0 + wn + j * 16 + l15)] = f2e4m3(e);
                rsum += e;
            }
#pragma unroll
            for (int o = 1; o < 16; o <<= 1) rsum += __shfl_xor(rsum, o);
            if (l15 == 0) atomicAdd(&l[row], rsum);
        }
}

// K4: out = (E @ g)/l + (em/gden)*gsum + x
__global__ __launch_bounds__(256, 2) void k_out(
        const char* __restrict__ E, const char* __restrict__ gbt,
        const float* __restrict__ l, const float* __restrict__ em,
        const float* __restrict__ gden, const float* __restrict__ gsum,
        const float* __restrict__ x, float* __restrict__ out) {
    __shared__ __align__(16) char smem[32768];
    int bm, bn; tile_coords(blockIdx.x, 8, bm, bn);
    int m0 = bm * 128, n0 = bn * 128;
    v4f acc[4][4];
    gemm_core_mx(E, gbt, NT, m0, n0, smem, acc);

    const float ginv = 1.f / gden[0];
    const int tid = threadIdx.x, wave = tid >> 6, lane = tid & 63;
    const int l15 = lane & 15, l4 = lane >> 4;
    const int wm = (wave >> 1) << 6, wn = (wave & 1) << 6;
#pragma unroll
    for (int i = 0; i < 4; i++)
#pragma unroll
        for (int v = 0; v < 4; v++) {
            int row = m0 + wm + i * 16 + l4 * 4 + v;
            float inv = 1.f / l[row];
            float gv  = em[row] * ginv;
#pragma unroll
            for (int j = 0; j < 4; j++) {
                int col = n0 + wn + j * 16 + l15;
                out[(size_t)row * DD + col] =
                    acc[i][j][v] * inv + gv * gsum[col] + x[(size_t)row * DD + col];
            }
        }
}

// ---------------- launch ----------------

extern "C" void kernel_launch(void* const* d_in, const int* in_sizes, int n_in,
                              void* d_out, int out_size, void* d_ws, size_t ws_size,
                              hipStream_t stream) {
    const float* x  = (const float*)d_in[0];
    const float* Wq = (const float*)d_in[1];
    const float* Wk = (const float*)d_in[2];
    const float* Wg = (const float*)d_in[3];
    const float* Wm = (const float*)d_in[4];
    const float* Wb = (const float*)d_in[5];
    const float* cp = (const float*)d_in[6];
    float* out = (float*)d_out;

    char* w = (char*)d_ws;
    size_t off = 0;
    auto alloc = [&](size_t bytes) -> void* {
        void* p = w + off;
        off += (bytes + 255) & ~(size_t)255;
        return p;
    };
    char*  q8    = (char*)alloc((size_t)NT * DD);           // 8 MB fp8 q_hat
    char*  k8    = (char*)alloc((size_t)NT * DD);           // 8 MB fp8 k_hat
    char*  gbt   = (char*)alloc((size_t)DD * NT);           // 8 MB fp8 g^T
    char*  w8t   = (char*)alloc((size_t)3 * DD * DD);       // 3 MB fp8 W^T*16
    char*  x8    = (char*)alloc((size_t)NT * DD);           // 8 MB fp8 x
    char*  E     = (char*)alloc((size_t)NT * NT);           // 64 MB fp8
    float* stats = (float*)alloc((2 * DD + 3 * NT + 1) * 4);
    float* qsum = stats;
    float* gsum = stats + DD;
    float* lrow = stats + 2 * DD;
    float* gden = lrow + NT;
    float* em   = gden + 1;
    float* beta = em + NT;
    if (off > ws_size) return;

    prep<<<2048 + 768, 256, 0, stream>>>(x, Wm, Wb, x8, em, Wq, Wk, Wg, w8t, stats);
    k_proj<<<64 * 24, 256, 0, stream>>>(x8, w8t, q8, k8, gbt, qsum, gsum);
    beta_gemv<<<2049, 256, 0, stream>>>(k8, qsum, cp, beta, em, gden);
    k_score<<<64 * 64, 256, 0, stream>>>(q8, k8, E, lrow, cp, beta);
    k_out<<<64 * 8, 256, 0, stream>>>(E, gbt, lrow, em, gden, gsum, x, out);
}

// Round 8
// 367.523 us; speedup vs baseline: 1.1909x; 1.0075x over previous
//
#include <hip/hip_runtime.h>
#include <math.h>

// N=8192 tokens, D=1024. All inputs fp32.
// out = (E@g)/l + gate*colsum(g) + x
// E = exp(c*q_hat@k_hat^T - beta_j), beta_j = c*mean(q_hat)·k_hat_j  (row-uniform
// centering terms cancel in E/rowsum(E)); gate = exp(m)/sum(exp(m)), no max needed.
// R8: fp8 core v2 — the d-dimension of x8/w8t/q8/k8 is stored PRE-PERMUTED within
// each 128-byte row (w' = pair*64 + l4*16 + half*8 + j) so each lane's two k-step
// fragments are one contiguous 16B chunk: 16 ds_read_b128/wave-iter instead of
// 32 ds_read_b64 -> LDS pipe no longer binds (was ~= MFMA pipe, MfmaUtil 48%).
// Dot products invariant under shared d-perm; qsum/beta use permuted indices.
// k_out MX core + E/gbt layouts untouched.

#define NT 8192
#define DD 1024

typedef float v4f __attribute__((ext_vector_type(4)));
typedef int   v4i __attribute__((ext_vector_type(4)));
typedef int   v8i __attribute__((ext_vector_type(8)));
typedef long  v2l __attribute__((ext_vector_type(2)));

typedef const __attribute__((address_space(1))) void* gp_t;
typedef __attribute__((address_space(3))) void* lp_t;

__device__ __forceinline__ char f2e4m3(float f) {
    unsigned p = __builtin_amdgcn_cvt_pk_fp8_f32(f, f, 0, false);
    return (char)(p & 0xff);
}
// d-permutation within a 128-byte block: w = kk + l4*8 + j  (kk in {0,32,64,96})
//   -> w' = (kk>=64)*64 + l4*16 + ((kk>>5)&1)*8 + j
__device__ __forceinline__ int permd(int w) {
    return ((w >> 6) << 6) | (((w >> 3) & 3) << 4) | (((w >> 5) & 1) << 3) | (w & 7);
}

// supertile swizzle: bands of 16 row-tiles so concurrent blocks share A/B panels in L2/LLC
__device__ __forceinline__ void tile_coords(int bid, int tn, int& bm, int& bn) {
    const int SUP = 16;
    int per = SUP * tn;
    int band = bid / per, r = bid % per;
    bm = band * SUP + (r % SUP);
    bn = r / SUP;
}

// ---------------- fp8 GEMM core v2 (k_proj, k_score; d-permuted inputs) ----------------
// A: [M x K] e4m3 row-major (K in BYTES, d-permuted), B: [N x K] e4m3 row-major (same perm).
// BK=128 bytes; per pair p in {0,1}: one b128/tile feeds two 16x16x32 k-steps.
__device__ __forceinline__ void gemm_core_fp8(const char* __restrict__ A,
                                              const char* __restrict__ B,
                                              int K, int m0, int n0,
                                              char* smem, v4f (&acc)[4][4])
{
    char* lsA = smem;             // 128 rows * 128 B
    char* lsB = smem + 16384;
    const int tid  = threadIdx.x;
    const int wave = tid >> 6, lane = tid & 63;
    const int l15 = lane & 15, l4 = lane >> 4;
    const int wm = (wave >> 1) << 6, wn = (wave & 1) << 6;

#pragma unroll
    for (int i = 0; i < 4; i++)
#pragma unroll
        for (int j = 0; j < 4; j++) acc[i][j] = (v4f)(0.0f);

    const int srow = lane >> 3;
    const int g    = (lane & 7) ^ srow;

    for (int k0 = 0; k0 < K; k0 += 128) {
#pragma unroll
        for (int i = 0; i < 4; i++) {
            int ci  = wave * 4 + i;
            int row = ci * 8 + srow;
            const char* ga = A + (size_t)(m0 + row) * K + k0 + g * 16;
            const char* gb = B + (size_t)(n0 + row) * K + k0 + g * 16;
            __builtin_amdgcn_global_load_lds((gp_t)ga, (lp_t)(lsA + ci * 1024), 16, 0, 0);
            __builtin_amdgcn_global_load_lds((gp_t)gb, (lp_t)(lsB + ci * 1024), 16, 0, 0);
        }
        __syncthreads();
#pragma unroll
        for (int p = 0; p < 2; p++) {
            v2l af[4], bq[4];
#pragma unroll
            for (int t = 0; t < 4; t++) {
                int ra = wm + t * 16 + l15;
                int ca = (p * 4 + l4) ^ (ra & 7);
                af[t] = *(const v2l*)(lsA + ra * 128 + ca * 16);
                int rb = wn + t * 16 + l15;
                int cb = (p * 4 + l4) ^ (rb & 7);
                bq[t] = *(const v2l*)(lsB + rb * 128 + cb * 16);
            }
#pragma unroll
            for (int i = 0; i < 4; i++)
#pragma unroll
                for (int j = 0; j < 4; j++)
                    acc[i][j] = __builtin_amdgcn_mfma_f32_16x16x32_fp8_fp8(af[i][0], bq[j][0], acc[i][j], 0, 0, 0);
#pragma unroll
            for (int i = 0; i < 4; i++)
#pragma unroll
                for (int j = 0; j < 4; j++)
                    acc[i][j] = __builtin_amdgcn_mfma_f32_16x16x32_fp8_fp8(af[i][1], bq[j][1], acc[i][j], 0, 0, 0);
        }
        __syncthreads();
    }
}

// ---------------- MX fp8 GEMM core v1 (k_out; unchanged) ----------------
__device__ __forceinline__ void gemm_core_mx(const char* __restrict__ A,
                                             const char* __restrict__ B,
                                             int K, int m0, int n0,
                                             char* smem, v4f (&acc)[4][4])
{
    char* lsA = smem;             // 128 rows * 128 B
    char* lsB = smem + 16384;
    const int tid  = threadIdx.x;
    const int wave = tid >> 6, lane = tid & 63;
    const int l15 = lane & 15, l4 = lane >> 4;
    const int wm = (wave >> 1) << 6, wn = (wave & 1) << 6;

#pragma unroll
    for (int i = 0; i < 4; i++)
#pragma unroll
        for (int j = 0; j < 4; j++) acc[i][j] = (v4f)(0.0f);

    const int srow = lane >> 3;
    const int g    = (lane & 7) ^ srow;

    for (int k0 = 0; k0 < K; k0 += 128) {
#pragma unroll
        for (int i = 0; i < 4; i++) {
            int ci  = wave * 4 + i;
            int row = ci * 8 + srow;
            const char* ga = A + (size_t)(m0 + row) * K + k0 + g * 16;
            const char* gb = B + (size_t)(n0 + row) * K + k0 + g * 16;
            __builtin_amdgcn_global_load_lds((gp_t)ga, (lp_t)(lsA + ci * 1024), 16, 0, 0);
            __builtin_amdgcn_global_load_lds((gp_t)gb, (lp_t)(lsB + ci * 1024), 16, 0, 0);
        }
        __syncthreads();
        v8i af[4], bq[4];
#pragma unroll
        for (int t = 0; t < 4; t++) {
            int ra = wm + t * 16 + l15;
            int a0 = (2 * l4) ^ (ra & 7), a1 = (2 * l4 + 1) ^ (ra & 7);
            v4i lo = *(const v4i*)(lsA + ra * 128 + a0 * 16);
            v4i hi = *(const v4i*)(lsA + ra * 128 + a1 * 16);
            af[t][0] = lo[0]; af[t][1] = lo[1]; af[t][2] = lo[2]; af[t][3] = lo[3];
            af[t][4] = hi[0]; af[t][5] = hi[1]; af[t][6] = hi[2]; af[t][7] = hi[3];
            int rb = wn + t * 16 + l15;
            int b0 = (2 * l4) ^ (rb & 7), b1 = (2 * l4 + 1) ^ (rb & 7);
            v4i blo = *(const v4i*)(lsB + rb * 128 + b0 * 16);
            v4i bhi = *(const v4i*)(lsB + rb * 128 + b1 * 16);
            bq[t][0] = blo[0]; bq[t][1] = blo[1]; bq[t][2] = blo[2]; bq[t][3] = blo[3];
            bq[t][4] = bhi[0]; bq[t][5] = bhi[1]; bq[t][6] = bhi[2]; bq[t][7] = bhi[3];
        }
#pragma unroll
        for (int i = 0; i < 4; i++)
#pragma unroll
            for (int j = 0; j < 4; j++)
                acc[i][j] = __builtin_amdgcn_mfma_scale_f32_16x16x128_f8f6f4(
                    af[i], bq[j], acc[i][j], 0, 0,
                    0, 0x7f7f7f7f, 0, 0x7f7f7f7f);   // e8m0 0x7f = 1.0
        __syncthreads();
    }
}

// ---------------- fused prep kernel ----------------
// blocks [0,2048): x -> e4m3 x8 (d-permuted); m = x.Wm + b; em = exp(m).
//   Block 0 zeroes stats.
// blocks [2048,2816): weight transpose + *16 + e4m3 cvt -> w8t (d-permuted).
__global__ void prep(const float* __restrict__ x, const float* __restrict__ wv,
                     const float* __restrict__ bp, char* __restrict__ x8,
                     float* __restrict__ em,
                     const float* __restrict__ Wq, const float* __restrict__ Wk,
                     const float* __restrict__ Wg, char* __restrict__ w8t,
                     float* __restrict__ zero_base) {
    __shared__ float t[64][68];
    int bid = blockIdx.x, tid = threadIdx.x;
    if (bid < 2048) {
        if (bid == 0) {
            for (int i = tid; i < 2 * DD + NT; i += 256) zero_base[i] = 0.f;
        }
        int wv_id = tid >> 6;
        int row = bid * 4 + wv_id;
        int lane = tid & 63;
        const float* xr = x + (size_t)row * DD;
        char* x8r = x8 + (size_t)row * DD;
        float s = 0.f;
        for (int c = lane * 4; c < DD; c += 256) {
            float4 a = *(const float4*)(xr + c);
            float4 b = *(const float4*)(wv + c);
            s = fmaf(a.x, b.x, s); s = fmaf(a.y, b.y, s);
            s = fmaf(a.z, b.z, s); s = fmaf(a.w, b.w, s);
            unsigned p = __builtin_amdgcn_cvt_pk_fp8_f32(a.x, a.y, 0, false);
            p = __builtin_amdgcn_cvt_pk_fp8_f32(a.z, a.w, p, true);
            int cp = (c & ~127) | permd(c & 127);    // c&7 == 0 or 4: 4 bytes stay contiguous
            *(int*)(x8r + cp) = (int)p;
        }
        for (int o = 32; o; o >>= 1) s += __shfl_down(s, o);
        if (lane == 0) em[row] = __expf(s + bp[0]);
    } else {
        int idx = bid - 2048;
        int bz = idx >> 8, rem = idx & 255;
        const float* W = bz == 0 ? Wq : (bz == 1 ? Wk : Wg);
        int k0 = (rem & 15) * 64, n0 = (rem >> 4) * 64;
        int tr = tid >> 4, tc = tid & 15;
#pragma unroll
        for (int p = 0; p < 4; p++) {
            int r = p * 16 + tr;
            float4 v = *(const float4*)(W + (size_t)(k0 + r) * DD + n0 + tc * 4);
            t[r][tc * 4 + 0] = v.x; t[r][tc * 4 + 1] = v.y;
            t[r][tc * 4 + 2] = v.z; t[r][tc * 4 + 3] = v.w;
        }
        __syncthreads();
#pragma unroll
        for (int p = 0; p < 4; p++) {
            int rr = p * 16 + tr;   // local n
            unsigned pk = __builtin_amdgcn_cvt_pk_fp8_f32(
                16.f * t[tc * 4 + 0][rr], 16.f * t[tc * 4 + 1][rr], 0, false);
            pk = __builtin_amdgcn_cvt_pk_fp8_f32(
                16.f * t[tc * 4 + 2][rr], 16.f * t[tc * 4 + 3][rr], pk, true);
            int kk = k0 + tc * 4;
            int kp = (kk & ~127) | permd(kk & 127);  // tc*4 -> j in {0,4}: contiguous
            *(int*)(w8t + (size_t)(bz * DD + n0 + rr) * DD + kp) = (int)pk;
        }
    }
}

// beta[j] = (c/NT) * sum_d qsum[d] * k8[j][d] (both d-permuted: sum invariant);
// block 2048 reduces em -> gden
__global__ void beta_gemv(const char* __restrict__ k8, const float* __restrict__ qsum,
                          const float* __restrict__ cp, float* __restrict__ beta,
                          const float* __restrict__ em, float* __restrict__ gden) {
    int tid = threadIdx.x, lane = tid & 63;
    if (blockIdx.x == 2048) {
        __shared__ float sr[4];
        float s = 0.f;
        for (int i = tid; i < NT; i += 256) s += em[i];
        for (int o = 32; o; o >>= 1) s += __shfl_xor(s, o);
        if (lane == 0) sr[tid >> 6] = s;
        __syncthreads();
        if (tid == 0) gden[0] = sr[0] + sr[1] + sr[2] + sr[3];
        return;
    }
    int row = blockIdx.x * 4 + (tid >> 6);
    v4i kv = *(const v4i*)(k8 + (size_t)row * DD + lane * 16);
    const float* qs = qsum + lane * 16;
    float s = 0.f;
#pragma unroll
    for (int w = 0; w < 4; w++) {
        float4 qv = *(const float4*)(qs + w * 4);
        int word = kv[w];
        s = fmaf(__builtin_amdgcn_cvt_f32_fp8(word, 0), qv.x, s);
        s = fmaf(__builtin_amdgcn_cvt_f32_fp8(word, 1), qv.y, s);
        s = fmaf(__builtin_amdgcn_cvt_f32_fp8(word, 2), qv.z, s);
        s = fmaf(__builtin_amdgcn_cvt_f32_fp8(word, 3), qv.w, s);
    }
    for (int o = 32; o; o >>= 1) s += __shfl_down(s, o);
    if (lane == 0) beta[row] = s * cp[0] / (float)NT;
}

// ---------------- GEMM kernels ----------------

// K1: C = (1/16) * x8 @ w8t^T  (M=8192, N=3072, K=1024 bytes), fp8 MFMA v2
__global__ __launch_bounds__(256, 2) void k_proj(
        const char* __restrict__ x8, const char* __restrict__ w8t,
        char* __restrict__ q8, char* __restrict__ k8, char* __restrict__ gbt,
        float* __restrict__ qsum, float* __restrict__ gsum) {
    __shared__ __align__(16) char smem[32768];
    int bm, bn; tile_coords(blockIdx.x, 24, bm, bn);
    int m0 = bm * 128, n0 = bn * 128;
    v4f acc[4][4];
    gemm_core_fp8(x8, w8t, DD, m0, n0, smem, acc);

    const int tid = threadIdx.x, wave = tid >> 6, lane = tid & 63;
    const int l15 = lane & 15, l4 = lane >> 4;
    const int wm = (wave >> 1) << 6, wn = (wave & 1) << 6;
    int sec = n0 >> 10;            // 0=q 1=k 2=g
    int nloc = n0 & (DD - 1);
    const float WS = 0.0625f;      // undo the *16 weight scale

    if (sec < 2) {
        // q8/k8 are consumed d-permuted by k_score/beta -> store at permuted col.
        char* dst = sec ? k8 : q8;
        float cs[4] = {0.f, 0.f, 0.f, 0.f};
#pragma unroll
        for (int i = 0; i < 4; i++)
#pragma unroll
            for (int j = 0; j < 4; j++) {
                int colp = nloc + permd(wn + j * 16 + l15);
#pragma unroll
                for (int v = 0; v < 4; v++) {
                    int row = m0 + wm + i * 16 + l4 * 4 + v;
                    float av = acc[i][j][v] * WS;
                    dst[(size_t)row * DD + colp] = f2e4m3(av);
                    cs[j] += av;
                }
            }
        if (sec == 0)
#pragma unroll
            for (int j = 0; j < 4; j++)
                atomicAdd(&qsum[nloc + permd(wn + j * 16 + l15)], cs[j]);
    } else {
        // g tile -> transposed fp8 store gbt[d][token] via LDS bounce (NOT permuted)
        char* sc = smem;
        float cs[4] = {0.f, 0.f, 0.f, 0.f};
#pragma unroll
        for (int i = 0; i < 4; i++)
#pragma unroll
            for (int j = 0; j < 4; j++)
#pragma unroll
                for (int v = 0; v < 4; v++) {
                    int lr = wn + j * 16 + l15;            // local d
                    int lc = wm + i * 16 + l4 * 4 + v;     // local token
                    float av = acc[i][j][v] * WS;
                    sc[lr * 144 + lc] = f2e4m3(av);
                    cs[j] += av;
                }
        __syncthreads();
#pragma unroll
        for (int it = 0; it < 4; it++) {
            int c = it * 256 + tid;
            int dr = c >> 3, cm = (c & 7) * 16;
            int4 vv = *(const int4*)(sc + dr * 144 + cm);
            *(int4*)(gbt + (size_t)(nloc + dr) * NT + m0 + cm) = vv;
        }
#pragma unroll
        for (int j = 0; j < 4; j++)
            atomicAdd(&gsum[nloc + wn + j * 16 + l15], cs[j]);
    }
}

// K3: E = exp(c*q@k^T - beta_j) e4m3, l += rowsum(E). E cols are token indices
// (B rows) -> unaffected by the d-perm.
__global__ __launch_bounds__(256, 2) void k_score(
        const char* __restrict__ q8, const char* __restrict__ k8,
        char* __restrict__ E, float* __restrict__ l, const float* __restrict__ cptr,
        const float* __restrict__ beta) {
    __shared__ __align__(16) char smem[32768];
    int bm, bn; tile_coords(blockIdx.x, 64, bm, bn);
    int m0 = bm * 128, n0 = bn * 128;
    v4f acc[4][4];
    gemm_core_fp8(q8, k8, DD, m0, n0, smem, acc);

    const float cv = cptr[0];
    const int tid = threadIdx.x, wave = tid >> 6, lane = tid & 63;
    const int l15 = lane & 15, l4 = lane >> 4;
    const int wm = (wave >> 1) << 6, wn = (wave & 1) << 6;
    float bj[4];
#pragma unroll
    for (int j = 0; j < 4; j++) bj[j] = beta[n0 + wn + j * 16 + l15];
#pragma unroll
    for (int i = 0; i < 4; i++)
#pragma unroll
        for (int v = 0; v < 4; v++) {
            int row = m0 + wm + i * 16 + l4 * 4 + v;
            float rsum = 0.f;
#pragma unroll
            for (int j = 0; j < 4; j++) {
                float e = __expf(cv * acc[i][j][v] - bj[j]);
                E[(size_t)row * NT + (n0 + wn + j * 16 + l15)] = f2e4m3(e);
                rsum += e;
            }
#pragma unroll
            for (int o = 1; o < 16; o <<= 1) rsum += __shfl_xor(rsum, o);
            if (l15 == 0) atomicAdd(&l[row], rsum);
        }
}

// K4: out = (E @ g)/l + (em/gden)*gsum + x
__global__ __launch_bounds__(256, 2) void k_out(
        const char* __restrict__ E, const char* __restrict__ gbt,
        const float* __restrict__ l, const float* __restrict__ em,
        const float* __restrict__ gden, const float* __restrict__ gsum,
        const float* __restrict__ x, float* __restrict__ out) {
    __shared__ __align__(16) char smem[32768];
    int bm, bn; tile_coords(blockIdx.x, 8, bm, bn);
    int m0 = bm * 128, n0 = bn * 128;
    v4f acc[4][4];
    gemm_core_mx(E, gbt, NT, m0, n0, smem, acc);

    const float ginv = 1.f / gden[0];
    const int tid = threadIdx.x, wave = tid >> 6, lane = tid & 63;
    const int l15 = lane & 15, l4 = lane >> 4;
    const int wm = (wave >> 1) << 6, wn = (wave & 1) << 6;
#pragma unroll
    for (int i = 0; i < 4; i++)
#pragma unroll
        for (int v = 0; v < 4; v++) {
            int row = m0 + wm + i * 16 + l4 * 4 + v;
            float inv = 1.f / l[row];
            float gv  = em[row] * ginv;
#pragma unroll
            for (int j = 0; j < 4; j++) {
                int col = n0 + wn + j * 16 + l15;
                out[(size_t)row * DD + col] =
                    acc[i][j][v] * inv + gv * gsum[col] + x[(size_t)row * DD + col];
            }
        }
}

// ---------------- launch ----------------

extern "C" void kernel_launch(void* const* d_in, const int* in_sizes, int n_in,
                              void* d_out, int out_size, void* d_ws, size_t ws_size,
                              hipStream_t stream) {
    const float* x  = (const float*)d_in[0];
    const float* Wq = (const float*)d_in[1];
    const float* Wk = (const float*)d_in[2];
    const float* Wg = (const float*)d_in[3];
    const float* Wm = (const float*)d_in[4];
    const float* Wb = (const float*)d_in[5];
    const float* cp = (const float*)d_in[6];
    float* out = (float*)d_out;

    char* w = (char*)d_ws;
    size_t off = 0;
    auto alloc = [&](size_t bytes) -> void* {
        void* p = w + off;
        off += (bytes + 255) & ~(size_t)255;
        return p;
    };
    char*  q8    = (char*)alloc((size_t)NT * DD);           // 8 MB fp8 q_hat (d-perm)
    char*  k8    = (char*)alloc((size_t)NT * DD);           // 8 MB fp8 k_hat (d-perm)
    char*  gbt   = (char*)alloc((size_t)DD * NT);           // 8 MB fp8 g^T
    char*  w8t   = (char*)alloc((size_t)3 * DD * DD);       // 3 MB fp8 W^T*16 (d-perm)
    char*  x8    = (char*)alloc((size_t)NT * DD);           // 8 MB fp8 x (d-perm)
    char*  E     = (char*)alloc((size_t)NT * NT);           // 64 MB fp8
    float* stats = (float*)alloc((2 * DD + 3 * NT + 1) * 4);
    float* qsum = stats;
    float* gsum = stats + DD;
    float* lrow = stats + 2 * DD;
    float* gden = lrow + NT;
    float* em   = gden + 1;
    float* beta = em + NT;
    if (off > ws_size) return;

    prep<<<2048 + 768, 256, 0, stream>>>(x, Wm, Wb, x8, em, Wq, Wk, Wg, w8t, stats);
    k_proj<<<64 * 24, 256, 0, stream>>>(x8, w8t, q8, k8, gbt, qsum, gsum);
    beta_gemv<<<2049, 256, 0, stream>>>(k8, qsum, cp, beta, em, gden);
    k_score<<<64 * 64, 256, 0, stream>>>(q8, k8, E, lrow, cp, beta);
    k_out<<<64 * 8, 256, 0, stream>>>(E, gbt, lrow, em, gden, gsum, x, out);
}